// Round 3
// baseline (355.180 us; speedup 1.0000x reference)
//
#include <hip/hip_runtime.h>
#include <hip/hip_bf16.h>
#include <stdint.h>

typedef __hip_bfloat16 bf16;
typedef __attribute__((ext_vector_type(8))) short short8;
typedef __attribute__((ext_vector_type(4))) short short4v;
typedef __attribute__((ext_vector_type(4))) float float4v;

static constexpr int nB = 2, nS = 2048, nD = 1024, nH = 16, nHD = 64;
static constexpr int nBS = nB * nS;   // 4096

#define AS_GLOBAL __attribute__((address_space(1)))
#define AS_LDS    __attribute__((address_space(3)))

union Frag16B { short8 v; uint4 u4; uint2 u2[2]; };

__device__ __forceinline__ void gload_lds16(const void* g, void* l) {
  __builtin_amdgcn_global_load_lds((AS_GLOBAL uint32_t*)(g), (AS_LDS uint32_t*)(l), 16, 0, 0);
}

__device__ __forceinline__ float fast_exp2(float x) {
#if __has_builtin(__builtin_amdgcn_exp2f)
  return __builtin_amdgcn_exp2f(x);
#else
  float r; asm volatile("v_exp_f32 %0, %1" : "=v"(r) : "v"(x)); return r;
#endif
}

// ---------------------------------------------------------------- prep: cast QKV->bf16, W->W^T bf16, rope tables
__global__ __launch_bounds__(256) void prep_kernel(
    const float* __restrict__ Qin, const float* __restrict__ Kin, const float* __restrict__ Vin,
    const float* __restrict__ Wq, const float* __restrict__ Wk,
    const float* __restrict__ Wv, const float* __restrict__ Wo,
    bf16* __restrict__ Qbf, bf16* __restrict__ Kbf, bf16* __restrict__ Vbf,
    bf16* __restrict__ WqT, bf16* __restrict__ WkT, bf16* __restrict__ WvT, bf16* __restrict__ WoT,
    bf16* __restrict__ cos_t, bf16* __restrict__ sin_t) {
  __shared__ float tile[64][65];
  int bx = blockIdx.x, t = threadIdx.x;
  if (bx < 3072) {
    int tz = bx >> 10, blk = bx & 1023;
    const float* src = tz == 0 ? Qin : tz == 1 ? Kin : Vin;
    bf16* dst = tz == 0 ? Qbf : tz == 1 ? Kbf : Vbf;
#pragma unroll
    for (int i = 0; i < 4; ++i) {
      int idx = blk * 1024 + i * 256 + t;  // float4 index
      float4 v = ((const float4*)src)[idx];
      union { bf16 b[4]; uint2 u; } tmp;
      tmp.b[0] = __float2bfloat16(v.x);
      tmp.b[1] = __float2bfloat16(v.y);
      tmp.b[2] = __float2bfloat16(v.z);
      tmp.b[3] = __float2bfloat16(v.w);
      ((uint2*)dst)[idx] = tmp.u;
    }
  } else if (bx < 4096) {
    int idx = bx - 3072;
    int z = idx >> 8;
    const float* W = z == 0 ? Wq : z == 1 ? Wk : z == 2 ? Wv : Wo;
    bf16* T = z == 0 ? WqT : z == 1 ? WkT : z == 2 ? WvT : WoT;
    int tk = (idx & 15) * 64, tn = ((idx >> 4) & 15) * 64;
    int c = t & 63, r0 = t >> 6;
#pragma unroll
    for (int i = 0; i < 16; ++i) {
      int r = i * 4 + r0;
      tile[r][c] = W[(size_t)(tk + r) * nD + tn + c];
    }
    __syncthreads();
#pragma unroll
    for (int i = 0; i < 16; ++i) {
      int r = i * 4 + r0;
      T[(size_t)(tn + r) * nD + tk + c] = __float2bfloat16(tile[c][r]);
    }
  } else {
    int base = (bx - 4096) * 1024 + t * 4;
#pragma unroll
    for (int i = 0; i < 4; ++i) {
      int e = base + i;
      int s = e >> 5, j = e & 31;
      float inv_freq = powf(100000.0f, -(float)(2 * j) / 64.0f);
      float g = (float)s * inv_freq;
      cos_t[e] = __float2bfloat16(cosf(g));
      sin_t[e] = __float2bfloat16(sinf(g));
    }
  }
}

// ---------------------------------------------------------------- fused projection GEMM, BK=64, xor-swizzled LDS
// grid (32, 8, 3): x = m-tile (A-tile sharers land on same XCD), y = n-tile
__global__ __launch_bounds__(256) void gemm_qkv_kernel(
    const bf16* __restrict__ A0, const bf16* __restrict__ A1, const bf16* __restrict__ A2,
    const bf16* __restrict__ Bt0, const bf16* __restrict__ Bt1, const bf16* __restrict__ Bt2,
    bf16* __restrict__ q_h, bf16* __restrict__ k_h, bf16* __restrict__ vt_h,
    const bf16* __restrict__ cos_t, const bf16* __restrict__ sin_t) {
  const int z = blockIdx.z;
  const bf16* A  = z == 0 ? A0 : (z == 1 ? A1 : A2);
  const bf16* Bt = z == 0 ? Bt0 : (z == 1 ? Bt1 : Bt2);

  __shared__ bf16 As[128 * 64];
  __shared__ bf16 Bs[128 * 64];

  const int t = threadIdx.x;
  const int lane = t & 63;
  const int wid = t >> 6;
  const int quad = lane >> 4;
  const int l16 = lane & 15;
  const int wm = wid >> 1;
  const int wn = wid & 1;
  const int m0 = blockIdx.x * 128;   // 32 m-tiles
  const int n0 = blockIdx.y * 128;   // 8 n-tiles
  const int K = nD;
  const int rloc = lane >> 3, cl = lane & 7;
  const int cg = cl ^ rloc;          // xor chunk swizzle (row&7 == rloc at staging)

  float4v acc[4][4] = {};

  for (int kt = 0; kt < K; kt += 64) {
    __syncthreads();
#pragma unroll
    for (int p = 0; p < 4; ++p) {
      int rowbase = (p * 4 + wid) * 8;
      gload_lds16(A + (size_t)(m0 + rowbase + rloc) * K + kt + cg * 8, As + (size_t)rowbase * 64);
      gload_lds16(Bt + (size_t)(n0 + rowbase + rloc) * K + kt + cg * 8, Bs + (size_t)rowbase * 64);
    }
    __syncthreads();

#pragma unroll
    for (int ks = 0; ks < 2; ++ks) {
      Frag16B a[4], b[4];
#pragma unroll
      for (int mi = 0; mi < 4; ++mi) {
        int row = wm * 64 + mi * 16 + l16;
        int ch = (ks * 4 + quad) ^ (row & 7);
        a[mi].u4 = *(const uint4*)&As[row * 64 + ch * 8];
      }
#pragma unroll
      for (int ni = 0; ni < 4; ++ni) {
        int row = wn * 64 + ni * 16 + l16;
        int ch = (ks * 4 + quad) ^ (row & 7);
        b[ni].u4 = *(const uint4*)&Bs[row * 64 + ch * 8];
      }
#pragma unroll
      for (int mi = 0; mi < 4; ++mi)
#pragma unroll
        for (int ni = 0; ni < 4; ++ni)
          acc[mi][ni] = __builtin_amdgcn_mfma_f32_16x16x32_bf16(a[mi].v, b[ni].v, acc[mi][ni], 0, 0, 0);
    }
  }

  const int col0 = n0 + wn * 64;   // multiple of 64 -> one head per wave
  if (z <= 1) {
    bf16* dst = z ? k_h : q_h;
#pragma unroll
    for (int mi = 0; mi < 4; ++mi)
#pragma unroll
      for (int r = 0; r < 4; ++r) {
        int row = m0 + wm * 64 + mi * 16 + quad * 4 + r;
        int s = row & (nS - 1);
        float x0 = acc[mi][0][r], x1 = acc[mi][1][r], x2 = acc[mi][2][r], x3 = acc[mi][3][r];
        float y[4];
#pragma unroll
        for (int p = 0; p < 2; ++p) {
          int d = p * 16 + l16;
          float c = __bfloat162float(cos_t[s * 32 + d]);
          float sn = __bfloat162float(sin_t[s * 32 + d]);
          float xa = p ? x1 : x0, xb = p ? x3 : x2;
          y[p] = xa * c + xb * sn;
          y[p + 2] = xb * c - xa * sn;
        }
        float ss = y[0] * y[0] + y[1] * y[1] + y[2] * y[2] + y[3] * y[3];
#pragma unroll
        for (int m = 1; m <= 8; m <<= 1) ss += __shfl_xor(ss, m, 64);
        float inv = 1.0f / sqrtf(ss * (1.0f / 64.0f) + 1e-9f);
#pragma unroll
        for (int ni = 0; ni < 4; ++ni)
          dst[(size_t)row * nD + col0 + ni * 16 + l16] = __float2bfloat16(y[ni] * inv);
      }
  } else {
    // V: write transposed -> vt_h [b][h][d][s]
#pragma unroll
    for (int mi = 0; mi < 4; ++mi)
#pragma unroll
      for (int r = 0; r < 4; ++r) {
        int row = m0 + wm * 64 + mi * 16 + quad * 4 + r;
        int b = row >> 11, s = row & (nS - 1);
#pragma unroll
        for (int ni = 0; ni < 4; ++ni) {
          int col = col0 + ni * 16 + l16;
          int h = col >> 6, d = col & 63;
          vt_h[((size_t)((b * nH + h) * 64 + d)) * nS + s] = __float2bfloat16(acc[mi][ni][r]);
        }
      }
  }
}

// ---------------------------------------------------------------- output GEMM: 64x128 tile, BK=64, grid (64, 8)
__global__ __launch_bounds__(256) void gemm_out_kernel(
    const bf16* __restrict__ A, const bf16* __restrict__ Bt, float* __restrict__ C) {
  __shared__ bf16 As[64 * 64];    // 8 KB
  __shared__ bf16 Bs[128 * 64];   // 16 KB
  const int t = threadIdx.x;
  const int lane = t & 63;
  const int wid = t >> 6;
  const int quad = lane >> 4;
  const int l16 = lane & 15;
  const int wm = wid >> 1;   // 0..1 (32-row slice)
  const int wn = wid & 1;    // 0..1 (64-col slice)
  const int m0 = blockIdx.x * 64;    // 64 m-tiles
  const int n0 = blockIdx.y * 128;   // 8 n-tiles
  const int K = nD;
  const int rloc = lane >> 3, cl = lane & 7;
  const int cg = cl ^ rloc;

  float4v acc[2][4] = {};
  for (int kt = 0; kt < K; kt += 64) {
    __syncthreads();
#pragma unroll
    for (int p = 0; p < 2; ++p) {
      int rowbase = (p * 4 + wid) * 8;
      gload_lds16(A + (size_t)(m0 + rowbase + rloc) * K + kt + cg * 8, As + (size_t)rowbase * 64);
    }
#pragma unroll
    for (int p = 0; p < 4; ++p) {
      int rowbase = (p * 4 + wid) * 8;
      gload_lds16(Bt + (size_t)(n0 + rowbase + rloc) * K + kt + cg * 8, Bs + (size_t)rowbase * 64);
    }
    __syncthreads();

#pragma unroll
    for (int ks = 0; ks < 2; ++ks) {
      Frag16B a[2], b[4];
#pragma unroll
      for (int mi = 0; mi < 2; ++mi) {
        int row = wm * 32 + mi * 16 + l16;
        int ch = (ks * 4 + quad) ^ (row & 7);
        a[mi].u4 = *(const uint4*)&As[row * 64 + ch * 8];
      }
#pragma unroll
      for (int ni = 0; ni < 4; ++ni) {
        int row = wn * 64 + ni * 16 + l16;
        int ch = (ks * 4 + quad) ^ (row & 7);
        b[ni].u4 = *(const uint4*)&Bs[row * 64 + ch * 8];
      }
#pragma unroll
      for (int mi = 0; mi < 2; ++mi)
#pragma unroll
        for (int ni = 0; ni < 4; ++ni)
          acc[mi][ni] = __builtin_amdgcn_mfma_f32_16x16x32_bf16(a[mi].v, b[ni].v, acc[mi][ni], 0, 0, 0);
    }
  }
#pragma unroll
  for (int mi = 0; mi < 2; ++mi)
#pragma unroll
    for (int ni = 0; ni < 4; ++ni)
#pragma unroll
      for (int r = 0; r < 4; ++r) {
        int row = m0 + wm * 32 + mi * 16 + quad * 4 + r;
        int col = n0 + wn * 64 + ni * 16 + l16;
        C[(size_t)row * nD + col] = acc[mi][ni][r];
      }
}

// ---------------------------------------------------------------- flash attention v3: LDS-free, barrier-free.
// S^T = K·Q^T via x32 MFMA (C layout row=key=quad*4+r, col=q=l16) feeds PV^T
// (O^T = V^T·P^T) via x16 MFMA whose B-operand layout (k=quad*4+j, n=l16) matches exactly.
static constexpr float SC = 0.18033688011112042f;  // 0.125 * log2(e)

__global__ __launch_bounds__(256) void attn_kernel(const bf16* __restrict__ q_h,
                                                   const bf16* __restrict__ k_h,
                                                   const bf16* __restrict__ vt_h,
                                                   bf16* __restrict__ vals) {
  const int t = threadIdx.x;
  const int lane = t & 63, wid = t >> 6, quad = lane >> 4, l16 = lane & 15;
  const int bh = blockIdx.y;
  const int b = bh >> 4, h = bh & 15;
  const int pairIdx = blockIdx.x;  // 0..15

  const bf16* Kbase = k_h + ((size_t)b * nS) * nD + h * 64;
  const bf16* Vbase = vt_h + (size_t)bh * 64 * nS;  // [d][s]

  for (int phase = 0; phase < 2; ++phase) {
    const int qt = phase == 0 ? (31 - pairIdx) : pairIdx;
    const int q_global = qt * 64 + wid * 16 + l16;

    // Q B-frags (n=q=l16, k=d=quad*8+j), 2 d-halves
    Frag16B qf[2];
    {
      const bf16* qp = q_h + ((size_t)(b * nS + q_global)) * nD + h * 64;
      qf[0].u4 = *(const uint4*)(qp + quad * 8);
      qf[1].u4 = *(const uint4*)(qp + 32 + quad * 8);
    }

    float4v o_acc[4] = {};
    float l_acc = 0.f;

    // preload K A-frags for kt=0 (m=key=l16, k=d=quad*8+j)
    Frag16B kf[4][2];
#pragma unroll
    for (int kt4 = 0; kt4 < 4; ++kt4) {
      const bf16* kp = Kbase + (size_t)(kt4 * 16 + l16) * nD + quad * 8;
      kf[kt4][0].u4 = *(const uint4*)(kp);
      kf[kt4][1].u4 = *(const uint4*)(kp + 32);
    }

    for (int kt = 0; kt <= qt; ++kt) {
      // V A-frags for x16 (m=d=l16, k=key=quad*4+j): straight from global
      uint2 vf[4][4];
#pragma unroll
      for (int dt = 0; dt < 4; ++dt) {
        const bf16* vp = Vbase + (size_t)(dt * 16 + l16) * nS + kt * 64 + quad * 4;
#pragma unroll
        for (int kt4 = 0; kt4 < 4; ++kt4)
          vf[dt][kt4] = *(const uint2*)(vp + kt4 * 16);
      }

      // S^T[key][q]
      float4v st[4];
#pragma unroll
      for (int kt4 = 0; kt4 < 4; ++kt4) {
        float4v zz = {};
        zz = __builtin_amdgcn_mfma_f32_16x16x32_bf16(kf[kt4][0].v, qf[0].v, zz, 0, 0, 0);
        st[kt4] = __builtin_amdgcn_mfma_f32_16x16x32_bf16(kf[kt4][1].v, qf[1].v, zz, 0, 0, 0);
      }

      // prefetch next K tile (full-iteration latency cover)
      if (kt < qt) {
#pragma unroll
        for (int kt4 = 0; kt4 < 4; ++kt4) {
          const bf16* kp = Kbase + (size_t)((kt + 1) * 64 + kt4 * 16 + l16) * nD + quad * 8;
          kf[kt4][0].u4 = *(const uint4*)(kp);
          kf[kt4][1].u4 = *(const uint4*)(kp + 32);
        }
      }

      // exp + pack P^T B-frags (k=key=quad*4+r matches C row)
      short4v pf[4];
      const bool diag = (kt == qt);
#pragma unroll
      for (int kt4 = 0; kt4 < 4; ++kt4) {
        int key0 = kt * 64 + kt4 * 16 + quad * 4;
#pragma unroll
        for (int r = 0; r < 4; ++r) {
          float x = st[kt4][r] * SC;
          if (diag && (key0 + r) > q_global) x = -12000.0f;
          float p = fast_exp2(x);
          l_acc += p;
          union { bf16 hh; short ss; } cv;
          cv.hh = __float2bfloat16(p);
          pf[kt4][r] = cv.ss;
        }
      }

      // PV^T: O^T[d][q]
#pragma unroll
      for (int dt = 0; dt < 4; ++dt) {
#pragma unroll
        for (int kt4 = 0; kt4 < 4; ++kt4) {
          union { uint2 u; short4v s; } vv;
          vv.u = vf[dt][kt4];
          o_acc[dt] = __builtin_amdgcn_mfma_f32_16x16x16bf16_1k(vv.s, pf[kt4], o_acc[dt], 0, 0, 0);
        }
      }
    }

    // l reduction across quads (each quad-group computed disjoint keys for q=l16)
    l_acc += __shfl_xor(l_acc, 16, 64);
    l_acc += __shfl_xor(l_acc, 32, 64);
    float inv_l = 1.0f / l_acc;

    // store: d = dt*16 + quad*4 + r, row = q_global
#pragma unroll
    for (int dt = 0; dt < 4; ++dt) {
      union { bf16 b4[4]; uint2 u; } ov;
#pragma unroll
      for (int r = 0; r < 4; ++r) ov.b4[r] = __float2bfloat16(o_acc[dt][r] * inv_l);
      *(uint2*)&vals[((size_t)(b * nS + q_global)) * nD + h * 64 + dt * 16 + quad * 4] = ov.u;
    }
  }
}

// ---------------------------------------------------------------- launch
extern "C" void kernel_launch(void* const* d_in, const int* in_sizes, int n_in,
                              void* d_out, int out_size, void* d_ws, size_t ws_size,
                              hipStream_t stream) {
  const float* Qin = (const float*)d_in[0];
  const float* Kin = (const float*)d_in[1];
  const float* Vin = (const float*)d_in[2];
  const float* Wq = (const float*)d_in[4];
  const float* Wk = (const float*)d_in[5];
  const float* Wv = (const float*)d_in[6];
  const float* Wo = (const float*)d_in[7];
  float* out = (float*)d_out;

  char* ws = (char*)d_ws;
  const size_t MB = 1u << 20;
  bf16* Qbf = (bf16*)(ws + 0 * MB);
  bf16* Kbf = (bf16*)(ws + 8 * MB);
  bf16* Vbf = (bf16*)(ws + 16 * MB);
  bf16* WqT = (bf16*)(ws + 24 * MB);
  bf16* WkT = (bf16*)(ws + 26 * MB);
  bf16* WvT = (bf16*)(ws + 28 * MB);
  bf16* WoT = (bf16*)(ws + 30 * MB);
  bf16* cos_t = (bf16*)(ws + 32 * MB);
  bf16* sin_t = (bf16*)(ws + 33 * MB);
  bf16* q_h = (bf16*)(ws + 34 * MB);
  bf16* k_h = (bf16*)(ws + 42 * MB);
  bf16* vt_h = (bf16*)(ws + 50 * MB);
  bf16* vals = (bf16*)(ws + 58 * MB);

  prep_kernel<<<4160, 256, 0, stream>>>(Qin, Kin, Vin, Wq, Wk, Wv, Wo,
                                        Qbf, Kbf, Vbf, WqT, WkT, WvT, WoT, cos_t, sin_t);

  gemm_qkv_kernel<<<dim3(32, 8, 3), 256, 0, stream>>>(Qbf, Kbf, Vbf, WqT, WkT, WvT,
                                                      q_h, k_h, vt_h, cos_t, sin_t);

  attn_kernel<<<dim3(16, 32), 256, 0, stream>>>(q_h, k_h, vt_h, vals);

  gemm_out_kernel<<<dim3(64, 8), 256, 0, stream>>>(vals, WoT, out);
}

// Round 4
// 263.840 us; speedup vs baseline: 1.3462x; 1.3462x over previous
//
#include <hip/hip_runtime.h>
#include <hip/hip_bf16.h>
#include <stdint.h>

typedef __hip_bfloat16 bf16;
typedef __attribute__((ext_vector_type(8))) short short8;
typedef __attribute__((ext_vector_type(4))) short short4v;
typedef __attribute__((ext_vector_type(4))) float float4v;

static constexpr int nB = 2, nS = 2048, nD = 1024, nH = 16, nHD = 64;
static constexpr int nBS = nB * nS;   // 4096

#define AS_GLOBAL __attribute__((address_space(1)))
#define AS_LDS    __attribute__((address_space(3)))

union Frag16B { short8 v; uint4 u4; uint2 u2[2]; };

__device__ __forceinline__ void gload_lds16(const void* g, void* l) {
  __builtin_amdgcn_global_load_lds((AS_GLOBAL uint32_t*)(g), (AS_LDS uint32_t*)(l), 16, 0, 0);
}

__device__ __forceinline__ float fast_exp2(float x) {
#if __has_builtin(__builtin_amdgcn_exp2f)
  return __builtin_amdgcn_exp2f(x);
#else
  float r; asm volatile("v_exp_f32 %0, %1" : "=v"(r) : "v"(x)); return r;
#endif
}

// drain LDS ops but NOT vmem: prefetch global loads stay in flight across the barrier
__device__ __forceinline__ void lds_barrier() {
  asm volatile("s_waitcnt lgkmcnt(0)\ns_barrier" ::: "memory");
}

// ---------------------------------------------------------------- prep: cast QKV->bf16, W->W^T bf16, rope tables
__global__ __launch_bounds__(256) void prep_kernel(
    const float* __restrict__ Qin, const float* __restrict__ Kin, const float* __restrict__ Vin,
    const float* __restrict__ Wq, const float* __restrict__ Wk,
    const float* __restrict__ Wv, const float* __restrict__ Wo,
    bf16* __restrict__ Qbf, bf16* __restrict__ Kbf, bf16* __restrict__ Vbf,
    bf16* __restrict__ WqT, bf16* __restrict__ WkT, bf16* __restrict__ WvT, bf16* __restrict__ WoT,
    bf16* __restrict__ cos_t, bf16* __restrict__ sin_t) {
  __shared__ float tile[64][65];
  int bx = blockIdx.x, t = threadIdx.x;
  if (bx < 3072) {
    int tz = bx >> 10, blk = bx & 1023;
    const float* src = tz == 0 ? Qin : tz == 1 ? Kin : Vin;
    bf16* dst = tz == 0 ? Qbf : tz == 1 ? Kbf : Vbf;
#pragma unroll
    for (int i = 0; i < 4; ++i) {
      int idx = blk * 1024 + i * 256 + t;  // float4 index
      float4 v = ((const float4*)src)[idx];
      union { bf16 b[4]; uint2 u; } tmp;
      tmp.b[0] = __float2bfloat16(v.x);
      tmp.b[1] = __float2bfloat16(v.y);
      tmp.b[2] = __float2bfloat16(v.z);
      tmp.b[3] = __float2bfloat16(v.w);
      ((uint2*)dst)[idx] = tmp.u;
    }
  } else if (bx < 4096) {
    int idx = bx - 3072;
    int z = idx >> 8;
    const float* W = z == 0 ? Wq : z == 1 ? Wk : z == 2 ? Wv : Wo;
    bf16* T = z == 0 ? WqT : z == 1 ? WkT : z == 2 ? WvT : WoT;
    int tk = (idx & 15) * 64, tn = ((idx >> 4) & 15) * 64;
    int c = t & 63, r0 = t >> 6;
#pragma unroll
    for (int i = 0; i < 16; ++i) {
      int r = i * 4 + r0;
      tile[r][c] = W[(size_t)(tk + r) * nD + tn + c];
    }
    __syncthreads();
#pragma unroll
    for (int i = 0; i < 16; ++i) {
      int r = i * 4 + r0;
      T[(size_t)(tn + r) * nD + tk + c] = __float2bfloat16(tile[c][r]);
    }
  } else {
    int base = (bx - 4096) * 1024 + t * 4;
#pragma unroll
    for (int i = 0; i < 4; ++i) {
      int e = base + i;
      int s = e >> 5, j = e & 31;
      float inv_freq = powf(100000.0f, -(float)(2 * j) / 64.0f);
      float g = (float)s * inv_freq;
      cos_t[e] = __float2bfloat16(cosf(g));
      sin_t[e] = __float2bfloat16(sinf(g));
    }
  }
}

// ---------------------------------------------------------------- fused projection GEMM, BK=64, xor-swizzled LDS
__global__ __launch_bounds__(256) void gemm_qkv_kernel(
    const bf16* __restrict__ A0, const bf16* __restrict__ A1, const bf16* __restrict__ A2,
    const bf16* __restrict__ Bt0, const bf16* __restrict__ Bt1, const bf16* __restrict__ Bt2,
    bf16* __restrict__ q_h, bf16* __restrict__ k_h, bf16* __restrict__ vt_h,
    const bf16* __restrict__ cos_t, const bf16* __restrict__ sin_t) {
  const int z = blockIdx.z;
  const bf16* A  = z == 0 ? A0 : (z == 1 ? A1 : A2);
  const bf16* Bt = z == 0 ? Bt0 : (z == 1 ? Bt1 : Bt2);

  __shared__ bf16 As[128 * 64];
  __shared__ bf16 Bs[128 * 64];

  const int t = threadIdx.x;
  const int lane = t & 63;
  const int wid = t >> 6;
  const int quad = lane >> 4;
  const int l16 = lane & 15;
  const int wm = wid >> 1;
  const int wn = wid & 1;
  const int m0 = blockIdx.x * 128;   // 32 m-tiles
  const int n0 = blockIdx.y * 128;   // 8 n-tiles
  const int K = nD;
  const int rloc = lane >> 3, cl = lane & 7;
  const int cg = cl ^ rloc;          // xor chunk swizzle

  float4v acc[4][4] = {};

  for (int kt = 0; kt < K; kt += 64) {
    __syncthreads();
#pragma unroll
    for (int p = 0; p < 4; ++p) {
      int rowbase = (p * 4 + wid) * 8;
      gload_lds16(A + (size_t)(m0 + rowbase + rloc) * K + kt + cg * 8, As + (size_t)rowbase * 64);
      gload_lds16(Bt + (size_t)(n0 + rowbase + rloc) * K + kt + cg * 8, Bs + (size_t)rowbase * 64);
    }
    __syncthreads();

#pragma unroll
    for (int ks = 0; ks < 2; ++ks) {
      Frag16B a[4], b[4];
#pragma unroll
      for (int mi = 0; mi < 4; ++mi) {
        int row = wm * 64 + mi * 16 + l16;
        int ch = (ks * 4 + quad) ^ (row & 7);
        a[mi].u4 = *(const uint4*)&As[row * 64 + ch * 8];
      }
#pragma unroll
      for (int ni = 0; ni < 4; ++ni) {
        int row = wn * 64 + ni * 16 + l16;
        int ch = (ks * 4 + quad) ^ (row & 7);
        b[ni].u4 = *(const uint4*)&Bs[row * 64 + ch * 8];
      }
#pragma unroll
      for (int mi = 0; mi < 4; ++mi)
#pragma unroll
        for (int ni = 0; ni < 4; ++ni)
          acc[mi][ni] = __builtin_amdgcn_mfma_f32_16x16x32_bf16(a[mi].v, b[ni].v, acc[mi][ni], 0, 0, 0);
    }
  }

  const int col0 = n0 + wn * 64;   // multiple of 64 -> one head per wave
  if (z <= 1) {
    bf16* dst = z ? k_h : q_h;
#pragma unroll
    for (int mi = 0; mi < 4; ++mi)
#pragma unroll
      for (int r = 0; r < 4; ++r) {
        int row = m0 + wm * 64 + mi * 16 + quad * 4 + r;
        int s = row & (nS - 1);
        float x0 = acc[mi][0][r], x1 = acc[mi][1][r], x2 = acc[mi][2][r], x3 = acc[mi][3][r];
        float y[4];
#pragma unroll
        for (int p = 0; p < 2; ++p) {
          int d = p * 16 + l16;
          float c = __bfloat162float(cos_t[s * 32 + d]);
          float sn = __bfloat162float(sin_t[s * 32 + d]);
          float xa = p ? x1 : x0, xb = p ? x3 : x2;
          y[p] = xa * c + xb * sn;
          y[p + 2] = xb * c - xa * sn;
        }
        float ss = y[0] * y[0] + y[1] * y[1] + y[2] * y[2] + y[3] * y[3];
#pragma unroll
        for (int m = 1; m <= 8; m <<= 1) ss += __shfl_xor(ss, m, 64);
        float inv = 1.0f / sqrtf(ss * (1.0f / 64.0f) + 1e-9f);
#pragma unroll
        for (int ni = 0; ni < 4; ++ni)
          dst[(size_t)row * nD + col0 + ni * 16 + l16] = __float2bfloat16(y[ni] * inv);
      }
  } else {
    // V: write transposed -> vt_h [b][h][d][s]
#pragma unroll
    for (int mi = 0; mi < 4; ++mi)
#pragma unroll
      for (int r = 0; r < 4; ++r) {
        int row = m0 + wm * 64 + mi * 16 + quad * 4 + r;
        int b = row >> 11, s = row & (nS - 1);
#pragma unroll
        for (int ni = 0; ni < 4; ++ni) {
          int col = col0 + ni * 16 + l16;
          int h = col >> 6, d = col & 63;
          vt_h[((size_t)((b * nH + h) * 64 + d)) * nS + s] = __float2bfloat16(acc[mi][ni][r]);
        }
      }
  }
}

// ---------------------------------------------------------------- output GEMM: 64x128 tile, BK=64, grid (64, 8)
__global__ __launch_bounds__(256) void gemm_out_kernel(
    const bf16* __restrict__ A, const bf16* __restrict__ Bt, float* __restrict__ C) {
  __shared__ bf16 As[64 * 64];
  __shared__ bf16 Bs[128 * 64];
  const int t = threadIdx.x;
  const int lane = t & 63;
  const int wid = t >> 6;
  const int quad = lane >> 4;
  const int l16 = lane & 15;
  const int wm = wid >> 1;
  const int wn = wid & 1;
  const int m0 = blockIdx.x * 64;
  const int n0 = blockIdx.y * 128;
  const int K = nD;
  const int rloc = lane >> 3, cl = lane & 7;
  const int cg = cl ^ rloc;

  float4v acc[2][4] = {};
  for (int kt = 0; kt < K; kt += 64) {
    __syncthreads();
#pragma unroll
    for (int p = 0; p < 2; ++p) {
      int rowbase = (p * 4 + wid) * 8;
      gload_lds16(A + (size_t)(m0 + rowbase + rloc) * K + kt + cg * 8, As + (size_t)rowbase * 64);
    }
#pragma unroll
    for (int p = 0; p < 4; ++p) {
      int rowbase = (p * 4 + wid) * 8;
      gload_lds16(Bt + (size_t)(n0 + rowbase + rloc) * K + kt + cg * 8, Bs + (size_t)rowbase * 64);
    }
    __syncthreads();

#pragma unroll
    for (int ks = 0; ks < 2; ++ks) {
      Frag16B a[2], b[4];
#pragma unroll
      for (int mi = 0; mi < 2; ++mi) {
        int row = wm * 32 + mi * 16 + l16;
        int ch = (ks * 4 + quad) ^ (row & 7);
        a[mi].u4 = *(const uint4*)&As[row * 64 + ch * 8];
      }
#pragma unroll
      for (int ni = 0; ni < 4; ++ni) {
        int row = wn * 64 + ni * 16 + l16;
        int ch = (ks * 4 + quad) ^ (row & 7);
        b[ni].u4 = *(const uint4*)&Bs[row * 64 + ch * 8];
      }
#pragma unroll
      for (int mi = 0; mi < 2; ++mi)
#pragma unroll
        for (int ni = 0; ni < 4; ++ni)
          acc[mi][ni] = __builtin_amdgcn_mfma_f32_16x16x32_bf16(a[mi].v, b[ni].v, acc[mi][ni], 0, 0, 0);
    }
  }
#pragma unroll
  for (int mi = 0; mi < 2; ++mi)
#pragma unroll
    for (int ni = 0; ni < 4; ++ni)
#pragma unroll
      for (int r = 0; r < 4; ++r) {
        int row = m0 + wm * 32 + mi * 16 + quad * 4 + r;
        int col = n0 + wn * 64 + ni * 16 + l16;
        C[(size_t)row * nD + col] = acc[mi][ni][r];
      }
}

// ---------------------------------------------------------------- flash attention v4: LDS-staged K/V (xor-swizzled),
// register-resident P. S^T = K·Q^T (C layout row=key=quad*4+r, col=q=l16) feeds
// O^T = V^T·P^T via x16 MFMA whose B-operand layout matches S^T's C layout exactly.
static constexpr float SC = 0.18033688011112042f;  // 0.125 * log2(e)

__global__ __launch_bounds__(256) void attn_kernel(const bf16* __restrict__ q_h,
                                                   const bf16* __restrict__ k_h,
                                                   const bf16* __restrict__ vt_h,
                                                   bf16* __restrict__ vals) {
  __shared__ bf16 Kl[2][64 * 64];
  __shared__ bf16 Vl[2][64 * 64];

  const int t = threadIdx.x;
  const int lane = t & 63, wid = t >> 6, quad = lane >> 4, l16 = lane & 15;
  const int bh = blockIdx.y;
  const int b = bh >> 4, h = bh & 15;
  const int pairIdx = blockIdx.x;  // 0..15

  const bf16* Kbase = k_h + ((size_t)b * nS) * nD + h * 64;
  const bf16* Vbase = vt_h + (size_t)bh * 64 * nS;  // [d][s]

  const int row0 = t >> 3;         // 0..31
  const int cl = t & 7;
  const int cg = cl ^ (row0 & 7);  // global chunk fetched into LDS chunk cl
  const int r7 = l16 & 7;

  for (int phase = 0; phase < 2; ++phase) {
    const int qt = phase == 0 ? (31 - pairIdx) : pairIdx;
    const int q_global = qt * 64 + wid * 16 + l16;

    // Q B-frags (n=q=l16, k=d=quad*8+j), 2 d-halves
    Frag16B qf[2];
    {
      const bf16* qp = q_h + ((size_t)(b * nS + q_global)) * nD + h * 64;
      qf[0].u4 = *(const uint4*)(qp + quad * 8);
      qf[1].u4 = *(const uint4*)(qp + 32 + quad * 8);
    }

    // prologue: load tile 0 into regs
    uint4 kreg[2], vreg[2];
#pragma unroll
    for (int i = 0; i < 2; ++i) {
      kreg[i] = *(const uint4*)(Kbase + (size_t)(row0 + i * 32) * nD + cg * 8);
      vreg[i] = *(const uint4*)(Vbase + (size_t)(row0 + i * 32) * nS + cg * 8);
    }

    lds_barrier();  // phase boundary: prior phase's LDS reads complete

    float4v o_acc[4] = {};
    float l_acc = 0.f;

    for (int kt = 0; kt <= qt; ++kt) {
      bf16* Kb = Kl[kt & 1];
      bf16* Vb = Vl[kt & 1];
      // staged regs -> LDS (contiguous per wave, conflict-free)
#pragma unroll
      for (int i = 0; i < 2; ++i) {
        *(uint4*)&Kb[(row0 + i * 32) * 64 + cl * 8] = kreg[i];
        *(uint4*)&Vb[(row0 + i * 32) * 64 + cl * 8] = vreg[i];
      }
      // prefetch next tile (global loads stay in flight across the barrier)
      if (kt < qt) {
#pragma unroll
        for (int i = 0; i < 2; ++i) {
          kreg[i] = *(const uint4*)(Kbase + (size_t)((kt + 1) * 64 + row0 + i * 32) * nD + cg * 8);
          vreg[i] = *(const uint4*)(Vbase + (size_t)(row0 + i * 32) * nS + (kt + 1) * 64 + cg * 8);
        }
      }
      lds_barrier();

      // S^T[key][q]: A = K frags from LDS (m=key=l16 within 16-row group, k=d)
      float4v st[4];
#pragma unroll
      for (int kt4 = 0; kt4 < 4; ++kt4) {
        int row = kt4 * 16 + l16;
        Frag16B k0, k1;
        k0.u4 = *(const uint4*)&Kb[row * 64 + ((quad ^ r7) * 8)];
        k1.u4 = *(const uint4*)&Kb[row * 64 + (((quad + 4) ^ r7) * 8)];
        float4v zz = {};
        zz = __builtin_amdgcn_mfma_f32_16x16x32_bf16(k0.v, qf[0].v, zz, 0, 0, 0);
        st[kt4] = __builtin_amdgcn_mfma_f32_16x16x32_bf16(k1.v, qf[1].v, st[kt4] = zz, 0, 0, 0);
      }

      // exp + pack P^T B-frags (k=key=quad*4+r matches C row) — no max, no rescale
      short4v pf[4];
      const bool diag = (kt == qt);
#pragma unroll
      for (int kt4 = 0; kt4 < 4; ++kt4) {
        int key0 = kt * 64 + kt4 * 16 + quad * 4;
#pragma unroll
        for (int r = 0; r < 4; ++r) {
          float x = st[kt4][r] * SC;
          if (diag && (key0 + r) > q_global) x = -12000.0f;
          float p = fast_exp2(x);
          l_acc += p;
          union { bf16 hh; short ss; } cv;
          cv.hh = __float2bfloat16(p);
          pf[kt4][r] = cv.ss;
        }
      }

      // O^T[d][q] += V^T·P^T : A = V frags from LDS (m=d=l16 group, k=key)
#pragma unroll
      for (int dt = 0; dt < 4; ++dt) {
        int row = dt * 16 + l16;
#pragma unroll
        for (int kt4 = 0; kt4 < 4; ++kt4) {
          int chunk = kt4 * 2 + (quad >> 1);
          union { uint2 u; short4v s; } vv;
          vv.u = *(const uint2*)&Vb[row * 64 + ((chunk ^ r7) * 8) + (quad & 1) * 4];
          o_acc[dt] = __builtin_amdgcn_mfma_f32_16x16x16bf16_1k(vv.s, pf[kt4], o_acc[dt], 0, 0, 0);
        }
      }
    }

    // l reduction across quad-groups (disjoint key quarters for q=l16)
    l_acc += __shfl_xor(l_acc, 16, 64);
    l_acc += __shfl_xor(l_acc, 32, 64);
    float inv_l = 1.0f / l_acc;

    // store: d = dt*16 + quad*4 + r, row = q_global
#pragma unroll
    for (int dt = 0; dt < 4; ++dt) {
      union { bf16 b4[4]; uint2 u; } ov;
#pragma unroll
      for (int r = 0; r < 4; ++r) ov.b4[r] = __float2bfloat16(o_acc[dt][r] * inv_l);
      *(uint2*)&vals[((size_t)(b * nS + q_global)) * nD + h * 64 + dt * 16 + quad * 4] = ov.u;
    }
  }
}

// ---------------------------------------------------------------- launch
extern "C" void kernel_launch(void* const* d_in, const int* in_sizes, int n_in,
                              void* d_out, int out_size, void* d_ws, size_t ws_size,
                              hipStream_t stream) {
  const float* Qin = (const float*)d_in[0];
  const float* Kin = (const float*)d_in[1];
  const float* Vin = (const float*)d_in[2];
  const float* Wq = (const float*)d_in[4];
  const float* Wk = (const float*)d_in[5];
  const float* Wv = (const float*)d_in[6];
  const float* Wo = (const float*)d_in[7];
  float* out = (float*)d_out;

  char* ws = (char*)d_ws;
  const size_t MB = 1u << 20;
  bf16* Qbf = (bf16*)(ws + 0 * MB);
  bf16* Kbf = (bf16*)(ws + 8 * MB);
  bf16* Vbf = (bf16*)(ws + 16 * MB);
  bf16* WqT = (bf16*)(ws + 24 * MB);
  bf16* WkT = (bf16*)(ws + 26 * MB);
  bf16* WvT = (bf16*)(ws + 28 * MB);
  bf16* WoT = (bf16*)(ws + 30 * MB);
  bf16* cos_t = (bf16*)(ws + 32 * MB);
  bf16* sin_t = (bf16*)(ws + 33 * MB);
  bf16* q_h = (bf16*)(ws + 34 * MB);
  bf16* k_h = (bf16*)(ws + 42 * MB);
  bf16* vt_h = (bf16*)(ws + 50 * MB);
  bf16* vals = (bf16*)(ws + 58 * MB);

  prep_kernel<<<4160, 256, 0, stream>>>(Qin, Kin, Vin, Wq, Wk, Wv, Wo,
                                        Qbf, Kbf, Vbf, WqT, WkT, WvT, WoT, cos_t, sin_t);

  gemm_qkv_kernel<<<dim3(32, 8, 3), 256, 0, stream>>>(Qbf, Kbf, Vbf, WqT, WkT, WvT,
                                                      q_h, k_h, vt_h, cos_t, sin_t);

  attn_kernel<<<dim3(16, 32), 256, 0, stream>>>(q_h, k_h, vt_h, vals);

  gemm_out_kernel<<<dim3(64, 8), 256, 0, stream>>>(vals, WoT, out);
}

// Round 6
// 248.575 us; speedup vs baseline: 1.4289x; 1.0614x over previous
//
#include <hip/hip_runtime.h>
#include <hip/hip_bf16.h>
#include <stdint.h>

typedef __hip_bfloat16 bf16;
typedef __attribute__((ext_vector_type(8))) short short8;
typedef __attribute__((ext_vector_type(4))) short short4v;
typedef __attribute__((ext_vector_type(4))) float float4v;

static constexpr int nB = 2, nS = 2048, nD = 1024, nH = 16, nHD = 64;
static constexpr int nBS = nB * nS;   // 4096

#define AS_GLOBAL __attribute__((address_space(1)))
#define AS_LDS    __attribute__((address_space(3)))

union Frag16B { short8 v; uint4 u4; uint2 u2[2]; };

__device__ __forceinline__ void gload_lds16(const void* g, void* l) {
  __builtin_amdgcn_global_load_lds((AS_GLOBAL uint32_t*)(g), (AS_LDS uint32_t*)(l), 16, 0, 0);
}

__device__ __forceinline__ float fast_exp2(float x) {
#if __has_builtin(__builtin_amdgcn_exp2f)
  return __builtin_amdgcn_exp2f(x);
#else
  float r; asm volatile("v_exp_f32 %0, %1" : "=v"(r) : "v"(x)); return r;
#endif
}

// drain LDS ops but NOT vmem: prefetch global loads stay in flight across the barrier
__device__ __forceinline__ void lds_barrier() {
  asm volatile("s_waitcnt lgkmcnt(0)\ns_barrier" ::: "memory");
}

__device__ __forceinline__ void lgkm_wait() {
  asm volatile("s_waitcnt lgkmcnt(0)" ::: "memory");
}

// ---------------------------------------------------------------- prep: cast QKV->bf16, W->W^T bf16, rope tables
__global__ __launch_bounds__(256) void prep_kernel(
    const float* __restrict__ Qin, const float* __restrict__ Kin, const float* __restrict__ Vin,
    const float* __restrict__ Wq, const float* __restrict__ Wk,
    const float* __restrict__ Wv, const float* __restrict__ Wo,
    bf16* __restrict__ Qbf, bf16* __restrict__ Kbf, bf16* __restrict__ Vbf,
    bf16* __restrict__ WqT, bf16* __restrict__ WkT, bf16* __restrict__ WvT, bf16* __restrict__ WoT,
    bf16* __restrict__ cos_t, bf16* __restrict__ sin_t) {
  __shared__ float tile[64][65];
  int bx = blockIdx.x, t = threadIdx.x;
  if (bx < 3072) {
    int tz = bx >> 10, blk = bx & 1023;
    const float* src = tz == 0 ? Qin : tz == 1 ? Kin : Vin;
    bf16* dst = tz == 0 ? Qbf : tz == 1 ? Kbf : Vbf;
#pragma unroll
    for (int i = 0; i < 4; ++i) {
      int idx = blk * 1024 + i * 256 + t;  // float4 index
      float4 v = ((const float4*)src)[idx];
      union { bf16 b[4]; uint2 u; } tmp;
      tmp.b[0] = __float2bfloat16(v.x);
      tmp.b[1] = __float2bfloat16(v.y);
      tmp.b[2] = __float2bfloat16(v.z);
      tmp.b[3] = __float2bfloat16(v.w);
      ((uint2*)dst)[idx] = tmp.u;
    }
  } else if (bx < 4096) {
    int idx = bx - 3072;
    int z = idx >> 8;
    const float* W = z == 0 ? Wq : z == 1 ? Wk : z == 2 ? Wv : Wo;
    bf16* T = z == 0 ? WqT : z == 1 ? WkT : z == 2 ? WvT : WoT;
    int tk = (idx & 15) * 64, tn = ((idx >> 4) & 15) * 64;
    int c = t & 63, r0 = t >> 6;
#pragma unroll
    for (int i = 0; i < 16; ++i) {
      int r = i * 4 + r0;
      tile[r][c] = W[(size_t)(tk + r) * nD + tn + c];
    }
    __syncthreads();
#pragma unroll
    for (int i = 0; i < 16; ++i) {
      int r = i * 4 + r0;
      T[(size_t)(tn + r) * nD + tk + c] = __float2bfloat16(tile[c][r]);
    }
  } else {
    int base = (bx - 4096) * 1024 + t * 4;
#pragma unroll
    for (int i = 0; i < 4; ++i) {
      int e = base + i;
      int s = e >> 5, j = e & 31;
      float inv_freq = powf(100000.0f, -(float)(2 * j) / 64.0f);
      float g = (float)s * inv_freq;
      cos_t[e] = __float2bfloat16(cosf(g));
      sin_t[e] = __float2bfloat16(sinf(g));
    }
  }
}

// ---------------------------------------------------------------- fused projection GEMM, BK=64, xor-swizzled LDS
__global__ __launch_bounds__(256) void gemm_qkv_kernel(
    const bf16* __restrict__ A0, const bf16* __restrict__ A1, const bf16* __restrict__ A2,
    const bf16* __restrict__ Bt0, const bf16* __restrict__ Bt1, const bf16* __restrict__ Bt2,
    bf16* __restrict__ q_h, bf16* __restrict__ k_h, bf16* __restrict__ vt_h,
    const bf16* __restrict__ cos_t, const bf16* __restrict__ sin_t) {
  const int z = blockIdx.z;
  const bf16* A  = z == 0 ? A0 : (z == 1 ? A1 : A2);
  const bf16* Bt = z == 0 ? Bt0 : (z == 1 ? Bt1 : Bt2);

  __shared__ bf16 As[128 * 64];
  __shared__ bf16 Bs[128 * 64];

  const int t = threadIdx.x;
  const int lane = t & 63;
  const int wid = t >> 6;
  const int quad = lane >> 4;
  const int l16 = lane & 15;
  const int wm = wid >> 1;
  const int wn = wid & 1;
  const int m0 = blockIdx.x * 128;   // 32 m-tiles
  const int n0 = blockIdx.y * 128;   // 8 n-tiles
  const int K = nD;
  const int rloc = lane >> 3, cl = lane & 7;
  const int cg = cl ^ rloc;          // xor chunk swizzle

  float4v acc[4][4] = {};

  for (int kt = 0; kt < K; kt += 64) {
    __syncthreads();
#pragma unroll
    for (int p = 0; p < 4; ++p) {
      int rowbase = (p * 4 + wid) * 8;
      gload_lds16(A + (size_t)(m0 + rowbase + rloc) * K + kt + cg * 8, As + (size_t)rowbase * 64);
      gload_lds16(Bt + (size_t)(n0 + rowbase + rloc) * K + kt + cg * 8, Bs + (size_t)rowbase * 64);
    }
    __syncthreads();

#pragma unroll
    for (int ks = 0; ks < 2; ++ks) {
      Frag16B a[4], b[4];
#pragma unroll
      for (int mi = 0; mi < 4; ++mi) {
        int row = wm * 64 + mi * 16 + l16;
        int ch = (ks * 4 + quad) ^ (row & 7);
        a[mi].u4 = *(const uint4*)&As[row * 64 + ch * 8];
      }
#pragma unroll
      for (int ni = 0; ni < 4; ++ni) {
        int row = wn * 64 + ni * 16 + l16;
        int ch = (ks * 4 + quad) ^ (row & 7);
        b[ni].u4 = *(const uint4*)&Bs[row * 64 + ch * 8];
      }
#pragma unroll
      for (int mi = 0; mi < 4; ++mi)
#pragma unroll
        for (int ni = 0; ni < 4; ++ni)
          acc[mi][ni] = __builtin_amdgcn_mfma_f32_16x16x32_bf16(a[mi].v, b[ni].v, acc[mi][ni], 0, 0, 0);
    }
  }

  const int col0 = n0 + wn * 64;   // multiple of 64 -> one head per wave
  if (z <= 1) {
    bf16* dst = z ? k_h : q_h;
#pragma unroll
    for (int mi = 0; mi < 4; ++mi)
#pragma unroll
      for (int r = 0; r < 4; ++r) {
        int row = m0 + wm * 64 + mi * 16 + quad * 4 + r;
        int s = row & (nS - 1);
        float x0 = acc[mi][0][r], x1 = acc[mi][1][r], x2 = acc[mi][2][r], x3 = acc[mi][3][r];
        float y[4];
#pragma unroll
        for (int p = 0; p < 2; ++p) {
          int d = p * 16 + l16;
          float c = __bfloat162float(cos_t[s * 32 + d]);
          float sn = __bfloat162float(sin_t[s * 32 + d]);
          float xa = p ? x1 : x0, xb = p ? x3 : x2;
          y[p] = xa * c + xb * sn;
          y[p + 2] = xb * c - xa * sn;
        }
        float ss = y[0] * y[0] + y[1] * y[1] + y[2] * y[2] + y[3] * y[3];
#pragma unroll
        for (int m = 1; m <= 8; m <<= 1) ss += __shfl_xor(ss, m, 64);
        float inv = 1.0f / sqrtf(ss * (1.0f / 64.0f) + 1e-9f);
#pragma unroll
        for (int ni = 0; ni < 4; ++ni)
          dst[(size_t)row * nD + col0 + ni * 16 + l16] = __float2bfloat16(y[ni] * inv);
      }
  } else {
    // V: write transposed -> vt_h [b][h][d][s]
#pragma unroll
    for (int mi = 0; mi < 4; ++mi)
#pragma unroll
      for (int r = 0; r < 4; ++r) {
        int row = m0 + wm * 64 + mi * 16 + quad * 4 + r;
        int b = row >> 11, s = row & (nS - 1);
#pragma unroll
        for (int ni = 0; ni < 4; ++ni) {
          int col = col0 + ni * 16 + l16;
          int h = col >> 6, d = col & 63;
          vt_h[((size_t)((b * nH + h) * 64 + d)) * nS + s] = __float2bfloat16(acc[mi][ni][r]);
        }
      }
  }
}

// ---------------------------------------------------------------- output GEMM: 64x128 tile, BK=64, grid (64, 8)
__global__ __launch_bounds__(256) void gemm_out_kernel(
    const bf16* __restrict__ A, const bf16* __restrict__ Bt, float* __restrict__ C) {
  __shared__ bf16 As[64 * 64];
  __shared__ bf16 Bs[128 * 64];
  const int t = threadIdx.x;
  const int lane = t & 63;
  const int wid = t >> 6;
  const int quad = lane >> 4;
  const int l16 = lane & 15;
  const int wm = wid >> 1;
  const int wn = wid & 1;
  const int m0 = blockIdx.x * 64;
  const int n0 = blockIdx.y * 128;
  const int K = nD;
  const int rloc = lane >> 3, cl = lane & 7;
  const int cg = cl ^ rloc;

  float4v acc[2][4] = {};
  for (int kt = 0; kt < K; kt += 64) {
    __syncthreads();
#pragma unroll
    for (int p = 0; p < 2; ++p) {
      int rowbase = (p * 4 + wid) * 8;
      gload_lds16(A + (size_t)(m0 + rowbase + rloc) * K + kt + cg * 8, As + (size_t)rowbase * 64);
    }
#pragma unroll
    for (int p = 0; p < 4; ++p) {
      int rowbase = (p * 4 + wid) * 8;
      gload_lds16(Bt + (size_t)(n0 + rowbase + rloc) * K + kt + cg * 8, Bs + (size_t)rowbase * 64);
    }
    __syncthreads();

#pragma unroll
    for (int ks = 0; ks < 2; ++ks) {
      Frag16B a[2], b[4];
#pragma unroll
      for (int mi = 0; mi < 2; ++mi) {
        int row = wm * 32 + mi * 16 + l16;
        int ch = (ks * 4 + quad) ^ (row & 7);
        a[mi].u4 = *(const uint4*)&As[row * 64 + ch * 8];
      }
#pragma unroll
      for (int ni = 0; ni < 4; ++ni) {
        int row = wn * 64 + ni * 16 + l16;
        int ch = (ks * 4 + quad) ^ (row & 7);
        b[ni].u4 = *(const uint4*)&Bs[row * 64 + ch * 8];
      }
#pragma unroll
      for (int mi = 0; mi < 2; ++mi)
#pragma unroll
        for (int ni = 0; ni < 4; ++ni)
          acc[mi][ni] = __builtin_amdgcn_mfma_f32_16x16x32_bf16(a[mi].v, b[ni].v, acc[mi][ni], 0, 0, 0);
    }
  }
#pragma unroll
  for (int mi = 0; mi < 2; ++mi)
#pragma unroll
    for (int ni = 0; ni < 4; ++ni)
#pragma unroll
      for (int r = 0; r < 4; ++r) {
        int row = m0 + wm * 32 + mi * 16 + quad * 4 + r;
        int col = n0 + wn * 64 + ni * 16 + l16;
        C[(size_t)row * nD + col] = acc[mi][ni][r];
      }
}

// ---------------------------------------------------------------- flash attention v5b: 128-q blocks, XCD-pinned bh,
// LDS-staged K/V (xor-swizzled, double-buffered, vmem-prefetch across lgkm-only barrier),
// register-resident P (S^T C-layout == x16 B-operand layout), LDS-transpose epilogue.
static constexpr float SC = 0.18033688011112042f;  // 0.125 * log2(e)

__global__ __launch_bounds__(256, 1) void attn_kernel(const bf16* __restrict__ q_h,
                                                      const bf16* __restrict__ k_h,
                                                      const bf16* __restrict__ vt_h,
                                                      bf16* __restrict__ vals) {
  __shared__ bf16 lds_buf[4 * 4096];   // [ K0 | K1 | V0 | V1 ]; front 4608 reused as epilogue scratch

  const int t = threadIdx.x;
  const int lane = t & 63, wid = t >> 6, quad = lane >> 4, l16 = lane & 15;
  const int id = blockIdx.x;
  const int xcd = id & 7, j = id >> 3;       // round-robin XCD heuristic
  const int bh = xcd * 4 + (j & 3);          // 4 heads per XCD -> K/V set fits L2
  const int pairIdx = j >> 2;                // 0..7
  const int b = bh >> 4, h = bh & 15;

  const bf16* Kbase = k_h + ((size_t)b * nS) * nD + h * 64;
  const bf16* Vbase = vt_h + (size_t)bh * 64 * nS;  // [d][s]

  const int row0 = t >> 3;         // 0..31
  const int cl = t & 7;
  const int cg = cl ^ (row0 & 7);  // global chunk fetched into LDS chunk cl
  const int r7 = l16 & 7;

  bf16* const scratch = lds_buf + wid * 1152;  // 16 x 72 per wave per qs round

  for (int phase = 0; phase < 2; ++phase) {
    const int qt = phase == 0 ? (15 - pairIdx) : pairIdx;   // 128-row q tile index
    const int nkt = 2 * qt + 2;
    const int q0w = qt * 128 + wid * 32;                    // wave's first q row

    // Q B-frags (n=q=l16, k=d=quad*8+j), 2 q-slices x 2 d-halves
    Frag16B qf[2][2];
#pragma unroll
    for (int qs = 0; qs < 2; ++qs) {
      const bf16* qp = q_h + ((size_t)(b * nS + q0w + qs * 16 + l16)) * nD + h * 64;
      qf[qs][0].u4 = *(const uint4*)(qp + quad * 8);
      qf[qs][1].u4 = *(const uint4*)(qp + 32 + quad * 8);
    }

    // prologue: load tile 0 into regs
    uint4 kreg[2], vreg[2];
#pragma unroll
    for (int i = 0; i < 2; ++i) {
      kreg[i] = *(const uint4*)(Kbase + (size_t)(row0 + i * 32) * nD + cg * 8);
      vreg[i] = *(const uint4*)(Vbase + (size_t)(row0 + i * 32) * nS + cg * 8);
    }

    lds_barrier();  // prior phase's LDS reads (incl. epilogue scratch) complete

    float4v o_acc[2][4] = {};
    float l_acc[2] = {0.f, 0.f};

    for (int kt = 0; kt < nkt; ++kt) {
      bf16* Kb = lds_buf + (kt & 1) * 4096;
      bf16* Vb = lds_buf + 8192 + (kt & 1) * 4096;
      // staged regs -> LDS (contiguous per wave, conflict-free)
#pragma unroll
      for (int i = 0; i < 2; ++i) {
        *(uint4*)&Kb[(row0 + i * 32) * 64 + cl * 8] = kreg[i];
        *(uint4*)&Vb[(row0 + i * 32) * 64 + cl * 8] = vreg[i];
      }
      // prefetch next tile (global loads stay in flight across the barrier)
      if (kt + 1 < nkt) {
#pragma unroll
        for (int i = 0; i < 2; ++i) {
          kreg[i] = *(const uint4*)(Kbase + (size_t)((kt + 1) * 64 + row0 + i * 32) * nD + cg * 8);
          vreg[i] = *(const uint4*)(Vbase + (size_t)(row0 + i * 32) * nS + (kt + 1) * 64 + cg * 8);
        }
      }
      lds_barrier();

      if (kt * 64 > q0w + 31) continue;   // fully-masked tile for this wave (stage-only)

      // S^T[key][q] for both q-slices; K frags shared
      float4v st[2][4];
#pragma unroll
      for (int kt4 = 0; kt4 < 4; ++kt4) {
        int row = kt4 * 16 + l16;
        Frag16B k0, k1;
        k0.u4 = *(const uint4*)&Kb[row * 64 + ((quad ^ r7) * 8)];
        k1.u4 = *(const uint4*)&Kb[row * 64 + (((quad + 4) ^ r7) * 8)];
#pragma unroll
        for (int qs = 0; qs < 2; ++qs) {
          float4v zz = {};
          zz = __builtin_amdgcn_mfma_f32_16x16x32_bf16(k0.v, qf[qs][0].v, zz, 0, 0, 0);
          st[qs][kt4] = __builtin_amdgcn_mfma_f32_16x16x32_bf16(k1.v, qf[qs][1].v, zz, 0, 0, 0);
        }
      }

      // exp + pack P^T B-frags (k=key=quad*4+r == C-layout row)
      short4v pf[2][4];
      const bool need_mask = (kt * 64 + 63) > q0w;   // wave-uniform
      if (need_mask) {
#pragma unroll
        for (int qs = 0; qs < 2; ++qs) {
          int qg = q0w + qs * 16 + l16;
#pragma unroll
          for (int kt4 = 0; kt4 < 4; ++kt4) {
            int key0 = kt * 64 + kt4 * 16 + quad * 4;
#pragma unroll
            for (int r = 0; r < 4; ++r) {
              float x = st[qs][kt4][r] * SC;
              if (key0 + r > qg) x = -12000.0f;
              float p = fast_exp2(x);
              l_acc[qs] += p;
              union { bf16 hh; short ss; } cv;
              cv.hh = __float2bfloat16(p);
              pf[qs][kt4][r] = cv.ss;
            }
          }
        }
      } else {
#pragma unroll
        for (int qs = 0; qs < 2; ++qs)
#pragma unroll
          for (int kt4 = 0; kt4 < 4; ++kt4)
#pragma unroll
            for (int r = 0; r < 4; ++r) {
              float p = fast_exp2(st[qs][kt4][r] * SC);
              l_acc[qs] += p;
              union { bf16 hh; short ss; } cv;
              cv.hh = __float2bfloat16(p);
              pf[qs][kt4][r] = cv.ss;
            }
      }

      // O^T[d][q] += V^T·P^T ; V frags shared across q-slices
#pragma unroll
      for (int dt = 0; dt < 4; ++dt) {
        int row = dt * 16 + l16;
#pragma unroll
        for (int kt4 = 0; kt4 < 4; ++kt4) {
          int chunk = kt4 * 2 + (quad >> 1);
          union { uint2 u; short4v s; } vv;
          vv.u = *(const uint2*)&Vb[row * 64 + ((chunk ^ r7) * 8) + (quad & 1) * 4];
          o_acc[0][dt] = __builtin_amdgcn_mfma_f32_16x16x16bf16_1k(vv.s, pf[0][kt4], o_acc[0][dt], 0, 0, 0);
          o_acc[1][dt] = __builtin_amdgcn_mfma_f32_16x16x16bf16_1k(vv.s, pf[1][kt4], o_acc[1][dt], 0, 0, 0);
        }
      }
    }

    // ---- epilogue: row-sum reduce, LDS-transpose, coalesced 16B stores
    lds_barrier();  // all waves done reading K/V before scratch overwrites them
#pragma unroll
    for (int qs = 0; qs < 2; ++qs) {
      float la = l_acc[qs];
      la += __shfl_xor(la, 16, 64);
      la += __shfl_xor(la, 32, 64);
      float inv_l = 1.0f / la;
      // write transposed: scratch[q_loc=l16][d]
#pragma unroll
      for (int dt = 0; dt < 4; ++dt) {
        union { bf16 b2[2]; uint u; } p01, p23;
        p01.b2[0] = __float2bfloat16(o_acc[qs][dt][0] * inv_l);
        p01.b2[1] = __float2bfloat16(o_acc[qs][dt][1] * inv_l);
        p23.b2[0] = __float2bfloat16(o_acc[qs][dt][2] * inv_l);
        p23.b2[1] = __float2bfloat16(o_acc[qs][dt][3] * inv_l);
        *(uint*)&scratch[l16 * 72 + dt * 16 + quad * 4] = p01.u;
        *(uint*)&scratch[l16 * 72 + dt * 16 + quad * 4 + 2] = p23.u;
      }
      lgkm_wait();  // own writes visible to own reads
      uint4 r0 = *(const uint4*)&scratch[l16 * 72 + quad * 16];
      uint4 r1 = *(const uint4*)&scratch[l16 * 72 + quad * 16 + 8];
      int qrow = q0w + qs * 16 + l16;
      bf16* vp = vals + ((size_t)(b * nS + qrow)) * nD + h * 64 + quad * 16;
      *(uint4*)(vp) = r0;
      *(uint4*)(vp + 8) = r1;
      lgkm_wait();  // reads done before next qs overwrites region
    }
  }
}

// ---------------------------------------------------------------- launch
extern "C" void kernel_launch(void* const* d_in, const int* in_sizes, int n_in,
                              void* d_out, int out_size, void* d_ws, size_t ws_size,
                              hipStream_t stream) {
  const float* Qin = (const float*)d_in[0];
  const float* Kin = (const float*)d_in[1];
  const float* Vin = (const float*)d_in[2];
  const float* Wq = (const float*)d_in[4];
  const float* Wk = (const float*)d_in[5];
  const float* Wv = (const float*)d_in[6];
  const float* Wo = (const float*)d_in[7];
  float* out = (float*)d_out;

  char* ws = (char*)d_ws;
  const size_t MB = 1u << 20;
  bf16* Qbf = (bf16*)(ws + 0 * MB);
  bf16* Kbf = (bf16*)(ws + 8 * MB);
  bf16* Vbf = (bf16*)(ws + 16 * MB);
  bf16* WqT = (bf16*)(ws + 24 * MB);
  bf16* WkT = (bf16*)(ws + 26 * MB);
  bf16* WvT = (bf16*)(ws + 28 * MB);
  bf16* WoT = (bf16*)(ws + 30 * MB);
  bf16* cos_t = (bf16*)(ws + 32 * MB);
  bf16* sin_t = (bf16*)(ws + 33 * MB);
  bf16* q_h = (bf16*)(ws + 34 * MB);
  bf16* k_h = (bf16*)(ws + 42 * MB);
  bf16* vt_h = (bf16*)(ws + 50 * MB);
  bf16* vals = (bf16*)(ws + 58 * MB);

  prep_kernel<<<4160, 256, 0, stream>>>(Qin, Kin, Vin, Wq, Wk, Wv, Wo,
                                        Qbf, Kbf, Vbf, WqT, WkT, WvT, WoT, cos_t, sin_t);

  gemm_qkv_kernel<<<dim3(32, 8, 3), 256, 0, stream>>>(Qbf, Kbf, Vbf, WqT, WkT, WvT,
                                                      q_h, k_h, vt_h, cos_t, sin_t);

  attn_kernel<<<256, 256, 0, stream>>>(q_h, k_h, vt_h, vals);

  gemm_out_kernel<<<dim3(64, 8), 256, 0, stream>>>(vals, WoT, out);
}

// Round 7
// 242.106 us; speedup vs baseline: 1.4670x; 1.0267x over previous
//
#include <hip/hip_runtime.h>
#include <hip/hip_bf16.h>
#include <stdint.h>

typedef __hip_bfloat16 bf16;
typedef __attribute__((ext_vector_type(8))) short short8;
typedef __attribute__((ext_vector_type(4))) short short4v;
typedef __attribute__((ext_vector_type(4))) float float4v;

static constexpr int nB = 2, nS = 2048, nD = 1024, nH = 16, nHD = 64;
static constexpr int nBS = nB * nS;   // 4096

#define AS_GLOBAL __attribute__((address_space(1)))
#define AS_LDS    __attribute__((address_space(3)))

union Frag16B { short8 v; uint4 u4; uint2 u2[2]; };

__device__ __forceinline__ void gload_lds16(const void* g, void* l) {
  __builtin_amdgcn_global_load_lds((AS_GLOBAL uint32_t*)(g), (AS_LDS uint32_t*)(l), 16, 0, 0);
}

__device__ __forceinline__ float fast_exp2(float x) {
#if __has_builtin(__builtin_amdgcn_exp2f)
  return __builtin_amdgcn_exp2f(x);
#else
  float r; asm volatile("v_exp_f32 %0, %1" : "=v"(r) : "v"(x)); return r;
#endif
}

// drain LDS ops but NOT vmem: prefetch global loads stay in flight across the barrier
__device__ __forceinline__ void lds_barrier() {
  asm volatile("s_waitcnt lgkmcnt(0)\ns_barrier" ::: "memory");
}

__device__ __forceinline__ void lgkm_wait() {
  asm volatile("s_waitcnt lgkmcnt(0)" ::: "memory");
}

// ---------------------------------------------------------------- prep: cast QKV->bf16, W->W^T bf16, rope tables
__global__ __launch_bounds__(256) void prep_kernel(
    const float* __restrict__ Qin, const float* __restrict__ Kin, const float* __restrict__ Vin,
    const float* __restrict__ Wq, const float* __restrict__ Wk,
    const float* __restrict__ Wv, const float* __restrict__ Wo,
    bf16* __restrict__ Qbf, bf16* __restrict__ Kbf, bf16* __restrict__ Vbf,
    bf16* __restrict__ WqT, bf16* __restrict__ WkT, bf16* __restrict__ WvT, bf16* __restrict__ WoT,
    bf16* __restrict__ cos_t, bf16* __restrict__ sin_t) {
  __shared__ float tile[64][65];
  int bx = blockIdx.x, t = threadIdx.x;
  if (bx < 3072) {
    int tz = bx >> 10, blk = bx & 1023;
    const float* src = tz == 0 ? Qin : tz == 1 ? Kin : Vin;
    bf16* dst = tz == 0 ? Qbf : tz == 1 ? Kbf : Vbf;
#pragma unroll
    for (int i = 0; i < 4; ++i) {
      int idx = blk * 1024 + i * 256 + t;  // float4 index
      float4 v = ((const float4*)src)[idx];
      union { bf16 b[4]; uint2 u; } tmp;
      tmp.b[0] = __float2bfloat16(v.x);
      tmp.b[1] = __float2bfloat16(v.y);
      tmp.b[2] = __float2bfloat16(v.z);
      tmp.b[3] = __float2bfloat16(v.w);
      ((uint2*)dst)[idx] = tmp.u;
    }
  } else if (bx < 4096) {
    int idx = bx - 3072;
    int z = idx >> 8;
    const float* W = z == 0 ? Wq : z == 1 ? Wk : z == 2 ? Wv : Wo;
    bf16* T = z == 0 ? WqT : z == 1 ? WkT : z == 2 ? WvT : WoT;
    int tk = (idx & 15) * 64, tn = ((idx >> 4) & 15) * 64;
    int c = t & 63, r0 = t >> 6;
#pragma unroll
    for (int i = 0; i < 16; ++i) {
      int r = i * 4 + r0;
      tile[r][c] = W[(size_t)(tk + r) * nD + tn + c];
    }
    __syncthreads();
#pragma unroll
    for (int i = 0; i < 16; ++i) {
      int r = i * 4 + r0;
      T[(size_t)(tn + r) * nD + tk + c] = __float2bfloat16(tile[c][r]);
    }
  } else {
    int base = (bx - 4096) * 1024 + t * 4;
#pragma unroll
    for (int i = 0; i < 4; ++i) {
      int e = base + i;
      int s = e >> 5, j = e & 31;
      float inv_freq = powf(100000.0f, -(float)(2 * j) / 64.0f);
      float g = (float)s * inv_freq;
      cos_t[e] = __float2bfloat16(cosf(g));
      sin_t[e] = __float2bfloat16(sinf(g));
    }
  }
}

// ---------------------------------------------------------------- fused projection GEMM, BK=64, xor-swizzled LDS
__global__ __launch_bounds__(256) void gemm_qkv_kernel(
    const bf16* __restrict__ A0, const bf16* __restrict__ A1, const bf16* __restrict__ A2,
    const bf16* __restrict__ Bt0, const bf16* __restrict__ Bt1, const bf16* __restrict__ Bt2,
    bf16* __restrict__ q_h, bf16* __restrict__ k_h, bf16* __restrict__ vt_h,
    const bf16* __restrict__ cos_t, const bf16* __restrict__ sin_t) {
  const int z = blockIdx.z;
  const bf16* A  = z == 0 ? A0 : (z == 1 ? A1 : A2);
  const bf16* Bt = z == 0 ? Bt0 : (z == 1 ? Bt1 : Bt2);

  __shared__ bf16 As[128 * 64];
  __shared__ bf16 Bs[128 * 64];

  const int t = threadIdx.x;
  const int lane = t & 63;
  const int wid = t >> 6;
  const int quad = lane >> 4;
  const int l16 = lane & 15;
  const int wm = wid >> 1;
  const int wn = wid & 1;
  const int m0 = blockIdx.x * 128;   // 32 m-tiles
  const int n0 = blockIdx.y * 128;   // 8 n-tiles
  const int K = nD;
  const int rloc = lane >> 3, cl = lane & 7;
  const int cg = cl ^ rloc;          // xor chunk swizzle

  float4v acc[4][4] = {};

  for (int kt = 0; kt < K; kt += 64) {
    __syncthreads();
#pragma unroll
    for (int p = 0; p < 4; ++p) {
      int rowbase = (p * 4 + wid) * 8;
      gload_lds16(A + (size_t)(m0 + rowbase + rloc) * K + kt + cg * 8, As + (size_t)rowbase * 64);
      gload_lds16(Bt + (size_t)(n0 + rowbase + rloc) * K + kt + cg * 8, Bs + (size_t)rowbase * 64);
    }
    __syncthreads();

#pragma unroll
    for (int ks = 0; ks < 2; ++ks) {
      Frag16B a[4], b[4];
#pragma unroll
      for (int mi = 0; mi < 4; ++mi) {
        int row = wm * 64 + mi * 16 + l16;
        int ch = (ks * 4 + quad) ^ (row & 7);
        a[mi].u4 = *(const uint4*)&As[row * 64 + ch * 8];
      }
#pragma unroll
      for (int ni = 0; ni < 4; ++ni) {
        int row = wn * 64 + ni * 16 + l16;
        int ch = (ks * 4 + quad) ^ (row & 7);
        b[ni].u4 = *(const uint4*)&Bs[row * 64 + ch * 8];
      }
#pragma unroll
      for (int mi = 0; mi < 4; ++mi)
#pragma unroll
        for (int ni = 0; ni < 4; ++ni)
          acc[mi][ni] = __builtin_amdgcn_mfma_f32_16x16x32_bf16(a[mi].v, b[ni].v, acc[mi][ni], 0, 0, 0);
    }
  }

  const int col0 = n0 + wn * 64;   // multiple of 64 -> one head per wave
  if (z <= 1) {
    bf16* dst = z ? k_h : q_h;
#pragma unroll
    for (int mi = 0; mi < 4; ++mi)
#pragma unroll
      for (int r = 0; r < 4; ++r) {
        int row = m0 + wm * 64 + mi * 16 + quad * 4 + r;
        int s = row & (nS - 1);
        float x0 = acc[mi][0][r], x1 = acc[mi][1][r], x2 = acc[mi][2][r], x3 = acc[mi][3][r];
        float y[4];
#pragma unroll
        for (int p = 0; p < 2; ++p) {
          int d = p * 16 + l16;
          float c = __bfloat162float(cos_t[s * 32 + d]);
          float sn = __bfloat162float(sin_t[s * 32 + d]);
          float xa = p ? x1 : x0, xb = p ? x3 : x2;
          y[p] = xa * c + xb * sn;
          y[p + 2] = xb * c - xa * sn;
        }
        float ss = y[0] * y[0] + y[1] * y[1] + y[2] * y[2] + y[3] * y[3];
#pragma unroll
        for (int m = 1; m <= 8; m <<= 1) ss += __shfl_xor(ss, m, 64);
        float inv = 1.0f / sqrtf(ss * (1.0f / 64.0f) + 1e-9f);
#pragma unroll
        for (int ni = 0; ni < 4; ++ni)
          dst[(size_t)row * nD + col0 + ni * 16 + l16] = __float2bfloat16(y[ni] * inv);
      }
  } else {
    // V: write transposed -> vt_h [b][h][d][s]
#pragma unroll
    for (int mi = 0; mi < 4; ++mi)
#pragma unroll
      for (int r = 0; r < 4; ++r) {
        int row = m0 + wm * 64 + mi * 16 + quad * 4 + r;
        int b = row >> 11, s = row & (nS - 1);
#pragma unroll
        for (int ni = 0; ni < 4; ++ni) {
          int col = col0 + ni * 16 + l16;
          int h = col >> 6, d = col & 63;
          vt_h[((size_t)((b * nH + h) * 64 + d)) * nS + s] = __float2bfloat16(acc[mi][ni][r]);
        }
      }
  }
}

// ---------------------------------------------------------------- output GEMM: 64x128 tile, BK=64, grid (64, 8)
__global__ __launch_bounds__(256) void gemm_out_kernel(
    const bf16* __restrict__ A, const bf16* __restrict__ Bt, float* __restrict__ C) {
  __shared__ bf16 As[64 * 64];
  __shared__ bf16 Bs[128 * 64];
  const int t = threadIdx.x;
  const int lane = t & 63;
  const int wid = t >> 6;
  const int quad = lane >> 4;
  const int l16 = lane & 15;
  const int wm = wid >> 1;
  const int wn = wid & 1;
  const int m0 = blockIdx.x * 64;
  const int n0 = blockIdx.y * 128;
  const int K = nD;
  const int rloc = lane >> 3, cl = lane & 7;
  const int cg = cl ^ rloc;

  float4v acc[2][4] = {};
  for (int kt = 0; kt < K; kt += 64) {
    __syncthreads();
#pragma unroll
    for (int p = 0; p < 2; ++p) {
      int rowbase = (p * 4 + wid) * 8;
      gload_lds16(A + (size_t)(m0 + rowbase + rloc) * K + kt + cg * 8, As + (size_t)rowbase * 64);
    }
#pragma unroll
    for (int p = 0; p < 4; ++p) {
      int rowbase = (p * 4 + wid) * 8;
      gload_lds16(Bt + (size_t)(n0 + rowbase + rloc) * K + kt + cg * 8, Bs + (size_t)rowbase * 64);
    }
    __syncthreads();

#pragma unroll
    for (int ks = 0; ks < 2; ++ks) {
      Frag16B a[2], b[4];
#pragma unroll
      for (int mi = 0; mi < 2; ++mi) {
        int row = wm * 32 + mi * 16 + l16;
        int ch = (ks * 4 + quad) ^ (row & 7);
        a[mi].u4 = *(const uint4*)&As[row * 64 + ch * 8];
      }
#pragma unroll
      for (int ni = 0; ni < 4; ++ni) {
        int row = wn * 64 + ni * 16 + l16;
        int ch = (ks * 4 + quad) ^ (row & 7);
        b[ni].u4 = *(const uint4*)&Bs[row * 64 + ch * 8];
      }
#pragma unroll
      for (int mi = 0; mi < 2; ++mi)
#pragma unroll
        for (int ni = 0; ni < 4; ++ni)
          acc[mi][ni] = __builtin_amdgcn_mfma_f32_16x16x32_bf16(a[mi].v, b[ni].v, acc[mi][ni], 0, 0, 0);
    }
  }
#pragma unroll
  for (int mi = 0; mi < 2; ++mi)
#pragma unroll
    for (int ni = 0; ni < 4; ++ni)
#pragma unroll
      for (int r = 0; r < 4; ++r) {
        int row = m0 + wm * 32 + mi * 16 + quad * 4 + r;
        int col = n0 + wn * 64 + ni * 16 + l16;
        C[(size_t)row * nD + col] = acc[mi][ni][r];
      }
}

// ---------------------------------------------------------------- flash attention v6: one 128-q tile per block,
// grid 512 = 2 blocks/CU (long+short causal tiles of the SAME head co-resident per CU),
// XCD-pinned bh, LDS-staged K/V double-buffered w/ vmem prefetch across lgkm-only barrier,
// register-resident P, LDS-transpose epilogue.
static constexpr float SC = 0.18033688011112042f;  // 0.125 * log2(e)

__global__ __launch_bounds__(256, 2) void attn_kernel(const bf16* __restrict__ q_h,
                                                      const bf16* __restrict__ k_h,
                                                      const bf16* __restrict__ vt_h,
                                                      bf16* __restrict__ vals) {
  __shared__ bf16 lds_buf[4 * 4096];   // [ K0 | K1 | V0 | V1 ]; front 4608 reused as epilogue scratch

  const int t = threadIdx.x;
  const int lane = t & 63, wid = t >> 6, quad = lane >> 4, l16 = lane & 15;
  const int id = blockIdx.x;           // 0..511
  const int xcd = id & 7;              // round-robin XCD heuristic (validated r5: FETCH 101->13MB)
  const int j = id >> 3;               // 0..63 per-XCD index
  const int jj = j & 31;
  const int bh = xcd * 4 + (jj & 3);   // 4 heads per XCD; pair blocks share bh
  const int u = jj >> 2;               // 0..7
  const int qt = (j < 32) ? (15 - u) : u;   // first CU-slot: long tiles; second: complementary short
  const int b = bh >> 4, h = bh & 15;

  const bf16* Kbase = k_h + ((size_t)b * nS) * nD + h * 64;
  const bf16* Vbase = vt_h + (size_t)bh * 64 * nS;  // [d][s]

  const int row0 = t >> 3;         // 0..31
  const int cl = t & 7;
  const int cg = cl ^ (row0 & 7);  // global chunk fetched into LDS chunk cl
  const int r7 = l16 & 7;

  bf16* const scratch = lds_buf + wid * 1152;  // 16 x 72 per wave per qs round

  const int nkt = 2 * qt + 2;
  const int q0w = qt * 128 + wid * 32;         // wave's first q row

  // Q B-frags (n=q=l16, k=d=quad*8+j), 2 q-slices x 2 d-halves
  Frag16B qf[2][2];
#pragma unroll
  for (int qs = 0; qs < 2; ++qs) {
    const bf16* qp = q_h + ((size_t)(b * nS + q0w + qs * 16 + l16)) * nD + h * 64;
    qf[qs][0].u4 = *(const uint4*)(qp + quad * 8);
    qf[qs][1].u4 = *(const uint4*)(qp + 32 + quad * 8);
  }

  // prologue: load tile 0 into regs
  uint4 kreg[2], vreg[2];
#pragma unroll
  for (int i = 0; i < 2; ++i) {
    kreg[i] = *(const uint4*)(Kbase + (size_t)(row0 + i * 32) * nD + cg * 8);
    vreg[i] = *(const uint4*)(Vbase + (size_t)(row0 + i * 32) * nS + cg * 8);
  }

  float4v o_acc[2][4] = {};
  float l_acc[2] = {0.f, 0.f};

  for (int kt = 0; kt < nkt; ++kt) {
    bf16* Kb = lds_buf + (kt & 1) * 4096;
    bf16* Vb = lds_buf + 8192 + (kt & 1) * 4096;
    // staged regs -> LDS (contiguous per wave, conflict-free)
#pragma unroll
    for (int i = 0; i < 2; ++i) {
      *(uint4*)&Kb[(row0 + i * 32) * 64 + cl * 8] = kreg[i];
      *(uint4*)&Vb[(row0 + i * 32) * 64 + cl * 8] = vreg[i];
    }
    // prefetch next tile (global loads stay in flight across the barrier)
    if (kt + 1 < nkt) {
#pragma unroll
      for (int i = 0; i < 2; ++i) {
        kreg[i] = *(const uint4*)(Kbase + (size_t)((kt + 1) * 64 + row0 + i * 32) * nD + cg * 8);
        vreg[i] = *(const uint4*)(Vbase + (size_t)(row0 + i * 32) * nS + (kt + 1) * 64 + cg * 8);
      }
    }
    lds_barrier();

    if (kt * 64 <= q0w + 31) {   // wave has unmasked keys in this tile
      // S^T[key][q] for both q-slices; K frags shared
      float4v st[2][4];
#pragma unroll
      for (int kt4 = 0; kt4 < 4; ++kt4) {
        int row = kt4 * 16 + l16;
        Frag16B k0, k1;
        k0.u4 = *(const uint4*)&Kb[row * 64 + ((quad ^ r7) * 8)];
        k1.u4 = *(const uint4*)&Kb[row * 64 + (((quad + 4) ^ r7) * 8)];
#pragma unroll
        for (int qs = 0; qs < 2; ++qs) {
          float4v zz = {};
          zz = __builtin_amdgcn_mfma_f32_16x16x32_bf16(k0.v, qf[qs][0].v, zz, 0, 0, 0);
          st[qs][kt4] = __builtin_amdgcn_mfma_f32_16x16x32_bf16(k1.v, qf[qs][1].v, zz, 0, 0, 0);
        }
      }

      // exp + pack P^T B-frags (k=key=quad*4+r == C-layout row)
      short4v pf[2][4];
      const bool need_mask = (kt * 64 + 63) > q0w;   // wave-uniform
      if (need_mask) {
#pragma unroll
        for (int qs = 0; qs < 2; ++qs) {
          int qg = q0w + qs * 16 + l16;
#pragma unroll
          for (int kt4 = 0; kt4 < 4; ++kt4) {
            int key0 = kt * 64 + kt4 * 16 + quad * 4;
#pragma unroll
            for (int r = 0; r < 4; ++r) {
              float x = st[qs][kt4][r] * SC;
              if (key0 + r > qg) x = -12000.0f;
              float p = fast_exp2(x);
              l_acc[qs] += p;
              union { bf16 hh; short ss; } cv;
              cv.hh = __float2bfloat16(p);
              pf[qs][kt4][r] = cv.ss;
            }
          }
        }
      } else {
#pragma unroll
        for (int qs = 0; qs < 2; ++qs)
#pragma unroll
          for (int kt4 = 0; kt4 < 4; ++kt4)
#pragma unroll
            for (int r = 0; r < 4; ++r) {
              float p = fast_exp2(st[qs][kt4][r] * SC);
              l_acc[qs] += p;
              union { bf16 hh; short ss; } cv;
              cv.hh = __float2bfloat16(p);
              pf[qs][kt4][r] = cv.ss;
            }
      }

      // O^T[d][q] += V^T·P^T ; V frags shared across q-slices
#pragma unroll
      for (int dt = 0; dt < 4; ++dt) {
        int row = dt * 16 + l16;
#pragma unroll
        for (int kt4 = 0; kt4 < 4; ++kt4) {
          int chunk = kt4 * 2 + (quad >> 1);
          union { uint2 u; short4v s; } vv;
          vv.u = *(const uint2*)&Vb[row * 64 + ((chunk ^ r7) * 8) + (quad & 1) * 4];
          o_acc[0][dt] = __builtin_amdgcn_mfma_f32_16x16x16bf16_1k(vv.s, pf[0][kt4], o_acc[0][dt], 0, 0, 0);
          o_acc[1][dt] = __builtin_amdgcn_mfma_f32_16x16x16bf16_1k(vv.s, pf[1][kt4], o_acc[1][dt], 0, 0, 0);
        }
      }
    }
  }

  // ---- epilogue: row-sum reduce, LDS-transpose, coalesced 16B stores
  lds_barrier();  // all waves done reading K/V before scratch overwrites them
#pragma unroll
  for (int qs = 0; qs < 2; ++qs) {
    float la = l_acc[qs];
    la += __shfl_xor(la, 16, 64);
    la += __shfl_xor(la, 32, 64);
    float inv_l = 1.0f / la;
    // write transposed: scratch[q_loc=l16][d]
#pragma unroll
    for (int dt = 0; dt < 4; ++dt) {
      union { bf16 b2[2]; uint u; } p01, p23;
      p01.b2[0] = __float2bfloat16(o_acc[qs][dt][0] * inv_l);
      p01.b2[1] = __float2bfloat16(o_acc[qs][dt][1] * inv_l);
      p23.b2[0] = __float2bfloat16(o_acc[qs][dt][2] * inv_l);
      p23.b2[1] = __float2bfloat16(o_acc[qs][dt][3] * inv_l);
      *(uint*)&scratch[l16 * 72 + dt * 16 + quad * 4] = p01.u;
      *(uint*)&scratch[l16 * 72 + dt * 16 + quad * 4 + 2] = p23.u;
    }
    lgkm_wait();  // own writes visible to own reads
    uint4 r0 = *(const uint4*)&scratch[l16 * 72 + quad * 16];
    uint4 r1 = *(const uint4*)&scratch[l16 * 72 + quad * 16 + 8];
    int qrow = q0w + qs * 16 + l16;
    bf16* vp = vals + ((size_t)(b * nS + qrow)) * nD + h * 64 + quad * 16;
    *(uint4*)(vp) = r0;
    *(uint4*)(vp + 8) = r1;
    lgkm_wait();  // reads done before next qs overwrites region
  }
}

// ---------------------------------------------------------------- launch
extern "C" void kernel_launch(void* const* d_in, const int* in_sizes, int n_in,
                              void* d_out, int out_size, void* d_ws, size_t ws_size,
                              hipStream_t stream) {
  const float* Qin = (const float*)d_in[0];
  const float* Kin = (const float*)d_in[1];
  const float* Vin = (const float*)d_in[2];
  const float* Wq = (const float*)d_in[4];
  const float* Wk = (const float*)d_in[5];
  const float* Wv = (const float*)d_in[6];
  const float* Wo = (const float*)d_in[7];
  float* out = (float*)d_out;

  char* ws = (char*)d_ws;
  const size_t MB = 1u << 20;
  bf16* Qbf = (bf16*)(ws + 0 * MB);
  bf16* Kbf = (bf16*)(ws + 8 * MB);
  bf16* Vbf = (bf16*)(ws + 16 * MB);
  bf16* WqT = (bf16*)(ws + 24 * MB);
  bf16* WkT = (bf16*)(ws + 26 * MB);
  bf16* WvT = (bf16*)(ws + 28 * MB);
  bf16* WoT = (bf16*)(ws + 30 * MB);
  bf16* cos_t = (bf16*)(ws + 32 * MB);
  bf16* sin_t = (bf16*)(ws + 33 * MB);
  bf16* q_h = (bf16*)(ws + 34 * MB);
  bf16* k_h = (bf16*)(ws + 42 * MB);
  bf16* vt_h = (bf16*)(ws + 50 * MB);
  bf16* vals = (bf16*)(ws + 58 * MB);

  prep_kernel<<<4160, 256, 0, stream>>>(Qin, Kin, Vin, Wq, Wk, Wv, Wo,
                                        Qbf, Kbf, Vbf, WqT, WkT, WvT, WoT, cos_t, sin_t);

  gemm_qkv_kernel<<<dim3(32, 8, 3), 256, 0, stream>>>(Qbf, Kbf, Vbf, WqT, WkT, WvT,
                                                      q_h, k_h, vt_h, cos_t, sin_t);

  attn_kernel<<<512, 256, 0, stream>>>(q_h, k_h, vt_h, vals);

  gemm_out_kernel<<<dim3(64, 8), 256, 0, stream>>>(vals, WoT, out);
}